// Round 1
// baseline (75.597 us; speedup 1.0000x reference)
//
#include <hip/hip_runtime.h>
#include <math.h>

#define BB 4
#define SS 4096
#define DIN 3
#define DK 5
#define TK 1024
#define NTHREADS 256

// ---------------------------------------------------------------------------
// Kernel 1: K^T / V^T projections into workspace, layout [B][DK][S] so the
// attention kernel's staging loads and LDS reads are contiguous per dim.
// ---------------------------------------------------------------------------
__global__ __launch_bounds__(NTHREADS) void proj_kv(
    const float* __restrict__ x,
    const float* __restrict__ Wk, const float* __restrict__ bk,
    const float* __restrict__ Wv, const float* __restrict__ bv,
    float* __restrict__ Kt, float* __restrict__ Vt)
{
    int gid = blockIdx.x * NTHREADS + threadIdx.x;   // over B*S rows
    if (gid >= BB * SS) return;
    int b = gid >> 12;           // / 4096
    int s = gid & (SS - 1);
    float x0 = x[gid * 3 + 0];
    float x1 = x[gid * 3 + 1];
    float x2 = x[gid * 3 + 2];
#pragma unroll
    for (int d = 0; d < DK; ++d) {
        float kv = fmaf(Wk[d * 3 + 0], x0, fmaf(Wk[d * 3 + 1], x1, fmaf(Wk[d * 3 + 2], x2, bk[d])));
        float vv = fmaf(Wv[d * 3 + 0], x0, fmaf(Wv[d * 3 + 1], x1, fmaf(Wv[d * 3 + 2], x2, bv[d])));
        Kt[((size_t)b * DK + d) * SS + s] = kv;   // consecutive s -> coalesced
        Vt[((size_t)b * DK + d) * SS + s] = vv;
    }
}

// ---------------------------------------------------------------------------
// Kernel 2: attention. Block = 256 threads = 8 row-groups x 32 key-split
// lanes; each thread owns 4 query rows (register row-blocking so each LDS
// key read feeds 4 rows). Online softmax: denominator over ALL keys,
// numerator only over keys <= row (mask applied after softmax).
// ---------------------------------------------------------------------------
__global__ __launch_bounds__(NTHREADS) void attn(
    const float* __restrict__ x,
    const float* __restrict__ Wq, const float* __restrict__ bq,
    const float* __restrict__ Kt, const float* __restrict__ Vt,
    float* __restrict__ out)
{
    __shared__ float kls[DK][TK];
    __shared__ float vls[DK][TK];

    const int tid = threadIdx.x;
    const int sub = tid & 31;        // key-split lane 0..31
    const int rowgrp = tid >> 5;     // 0..7

    const int blocksPerBatch = SS / 32;                 // 128
    const int b = blockIdx.x / blocksPerBatch;
    const int qbase = (blockIdx.x % blocksPerBatch) * 32;
    const int row0 = qbase + rowgrp * 4;

    // q for this thread's 4 rows (pre-scaled by 1/sqrt(5))
    const float scale = 0.44721359549995793f;
    float q[4][DK];
#pragma unroll
    for (int r = 0; r < 4; ++r) {
        const float* xr = &x[((size_t)b * SS + (row0 + r)) * 3];
        float x0 = xr[0], x1 = xr[1], x2 = xr[2];
#pragma unroll
        for (int d = 0; d < DK; ++d) {
            float qv = fmaf(Wq[d * 3 + 0], x0, fmaf(Wq[d * 3 + 1], x1, fmaf(Wq[d * 3 + 2], x2, bq[d])));
            q[r][d] = qv * scale;
        }
    }

    float m[4], l[4], acc[4][DK];
#pragma unroll
    for (int r = 0; r < 4; ++r) {
        m[r] = -1e30f;
        l[r] = 0.0f;
#pragma unroll
        for (int d = 0; d < DK; ++d) acc[r][d] = 0.0f;
    }

    const float* KtB = &Kt[(size_t)b * DK * SS];
    const float* VtB = &Vt[(size_t)b * DK * SS];

    for (int t = 0; t < SS; t += TK) {
        __syncthreads();
        // stage K/V tile (transposed [DK][TK]) -- 5 float4 per thread each
#pragma unroll
        for (int it = 0; it < (DK * TK / 4) / NTHREADS; ++it) {
            int idx = it * NTHREADS + tid;     // 0..1279
            int d = idx >> 8;                  // / (TK/4)
            int c4 = idx & 255;
            *(float4*)&kls[d][c4 * 4] = *(const float4*)&KtB[(size_t)d * SS + t + c4 * 4];
            *(float4*)&vls[d][c4 * 4] = *(const float4*)&VtB[(size_t)d * SS + t + c4 * 4];
        }
        __syncthreads();

#pragma unroll
        for (int j = 0; j < TK / 128; ++j) {   // 8 steps, 4 keys each
            const int key = j * 128 + sub * 4; // local key index (16B aligned)
            const int kg = t + key;            // global key index

            float kx[DK][4];
#pragma unroll
            for (int d = 0; d < DK; ++d)
                *(float4*)kx[d] = *(const float4*)&kls[d][key];

            // V only needed if any of these 4 keys can be <= any of our rows
            const bool needV = (kg <= row0 + 3);
            float vx[DK][4];
            if (needV) {
#pragma unroll
                for (int d = 0; d < DK; ++d)
                    *(float4*)vx[d] = *(const float4*)&vls[d][key];
            }

#pragma unroll
            for (int r = 0; r < 4; ++r) {
                const int row = row0 + r;
#pragma unroll
                for (int kk = 0; kk < 4; ++kk) {
                    float sc = q[r][0] * kx[0][kk];
#pragma unroll
                    for (int d = 1; d < DK; ++d) sc = fmaf(q[r][d], kx[d][kk], sc);
                    float p;
                    if (sc > m[r]) {           // rare path: new running max
                        float c = __expf(m[r] - sc);
                        m[r] = sc;
                        l[r] *= c;
#pragma unroll
                        for (int d = 0; d < DK; ++d) acc[r][d] *= c;
                        p = 1.0f;
                    } else {
                        p = __expf(sc - m[r]);
                    }
                    l[r] += p;                  // denominator: ALL keys
                    if (kg + kk <= row) {       // numerator: causal only
#pragma unroll
                        for (int d = 0; d < DK; ++d)
                            acc[r][d] = fmaf(p, vx[d][kk], acc[r][d]);
                    }
                }
            }
        }
    }

    // reduce across the 32 key-split lanes (xor butterfly stays in 32-half)
#pragma unroll
    for (int r = 0; r < 4; ++r) {
        float mr = m[r];
#pragma unroll
        for (int off = 16; off >= 1; off >>= 1)
            mr = fmaxf(mr, __shfl_xor(mr, off));
        float f = __expf(m[r] - mr);
        float lr = l[r] * f;
        float a0 = acc[r][0] * f, a1 = acc[r][1] * f, a2 = acc[r][2] * f;
        float a3 = acc[r][3] * f, a4 = acc[r][4] * f;
#pragma unroll
        for (int off = 16; off >= 1; off >>= 1) {
            lr += __shfl_xor(lr, off);
            a0 += __shfl_xor(a0, off);
            a1 += __shfl_xor(a1, off);
            a2 += __shfl_xor(a2, off);
            a3 += __shfl_xor(a3, off);
            a4 += __shfl_xor(a4, off);
        }
        if (sub < DK) {
            float av = sub == 0 ? a0 : sub == 1 ? a1 : sub == 2 ? a2 : sub == 3 ? a3 : a4;
            out[((size_t)b * SS + (row0 + r)) * DK + sub] = av / lr;
        }
    }
}

extern "C" void kernel_launch(void* const* d_in, const int* in_sizes, int n_in,
                              void* d_out, int out_size, void* d_ws, size_t ws_size,
                              hipStream_t stream) {
    const float* x  = (const float*)d_in[0];
    const float* Wq = (const float*)d_in[1];
    const float* bq = (const float*)d_in[2];
    const float* Wk = (const float*)d_in[3];
    const float* bk = (const float*)d_in[4];
    const float* Wv = (const float*)d_in[5];
    const float* bv = (const float*)d_in[6];
    float* outp = (float*)d_out;

    float* Kt = (float*)d_ws;                       // [B][DK][S]
    float* Vt = Kt + (size_t)BB * DK * SS;          // [B][DK][S]  (total 655 KB)

    proj_kv<<<(BB * SS + NTHREADS - 1) / NTHREADS, NTHREADS, 0, stream>>>(
        x, Wk, bk, Wv, bv, Kt, Vt);

    attn<<<BB * (SS / 32), NTHREADS, 0, stream>>>(
        x, Wq, bq, Kt, Vt, outp);
}

// Round 2
// 60.189 us; speedup vs baseline: 1.2560x; 1.2560x over previous
//
#include <hip/hip_runtime.h>
#include <math.h>

#define BB 4
#define SS 4096
#define DK 5
#define TK 1024
#define NT 256
// scale (1/sqrt(5)) * log2(e), folded into all score terms so p = v_exp_f32(sc)
#define LAM (0.44721359549995793f * 1.4426950408889634f)

__device__ __forceinline__ float fast_exp2(float x) {
#if __has_builtin(__builtin_amdgcn_exp2f)
    return __builtin_amdgcn_exp2f(x);
#else
    float r; asm("v_exp_f32 %0, %1" : "=v"(r) : "v"(x)); return r;
#endif
}

// ---------------------------------------------------------------------------
// Kernel 1: build K' = [x0,x1,x2,g] (g = LAM * (Wk^T bq)·x) and V^T in ws.
// Layout [B][4][S] and [B][5][S] so attn staging is coalesced per dim.
// ---------------------------------------------------------------------------
__global__ __launch_bounds__(NT) void proj_kv(
    const float* __restrict__ x,
    const float* __restrict__ Wk, const float* __restrict__ bq,
    const float* __restrict__ Wv, const float* __restrict__ bv,
    float* __restrict__ Kt, float* __restrict__ Vt)
{
    int gid = blockIdx.x * NT + threadIdx.x;   // over B*S rows
    if (gid >= BB * SS) return;
    int b = gid >> 12;
    int s = gid & (SS - 1);
    float x0 = x[gid * 3 + 0];
    float x1 = x[gid * 3 + 1];
    float x2 = x[gid * 3 + 2];

    // u = Wk^T bq
    float u0 = 0.f, u1 = 0.f, u2 = 0.f;
#pragma unroll
    for (int d = 0; d < DK; ++d) {
        float bqd = bq[d];
        u0 = fmaf(Wk[d * 3 + 0], bqd, u0);
        u1 = fmaf(Wk[d * 3 + 1], bqd, u1);
        u2 = fmaf(Wk[d * 3 + 2], bqd, u2);
    }
    float g = LAM * (u0 * x0 + u1 * x1 + u2 * x2);

    float* KtB = Kt + (size_t)b * 4 * SS;
    KtB[0 * SS + s] = x0;
    KtB[1 * SS + s] = x1;
    KtB[2 * SS + s] = x2;
    KtB[3 * SS + s] = g;

#pragma unroll
    for (int d = 0; d < DK; ++d) {
        float vv = fmaf(Wv[d * 3 + 0], x0, fmaf(Wv[d * 3 + 1], x1, fmaf(Wv[d * 3 + 2], x2, bv[d])));
        Vt[((size_t)b * DK + d) * SS + s] = vv;
    }
}

// ---------------------------------------------------------------------------
// Kernel 2: attention. 1024 blocks, 16 rows each (4 rowgroups x 64 key-split
// lanes; 4 rows/thread). No online max (scores bounded). Tiles split into
// pure-past / pure-future / mixed regimes.
// score = a_q · x_k + e_q + g_k, all pre-scaled by LAM, so p = exp2(score).
// ---------------------------------------------------------------------------
__global__ __launch_bounds__(NT) void attn(
    const float* __restrict__ x,
    const float* __restrict__ Wq, const float* __restrict__ bq,
    const float* __restrict__ Wk, const float* __restrict__ bk,
    const float* __restrict__ Kt, const float* __restrict__ Vt,
    float* __restrict__ out)
{
    __shared__ float kls[4][TK];
    __shared__ float vls[DK][TK];

    const int tid = threadIdx.x;
    const int sub = tid & 63;        // key-split lane (one wave = one rowgroup)
    const int rowgrp = tid >> 6;     // 0..3

    const int b = blockIdx.x >> 8;
    const int gblk = blockIdx.x & 255;
    // pair hi/lo qbase on adjacent blocks to balance per-CU load
    const int qidx = (gblk & 1) ? (255 - (gblk >> 1)) : (gblk >> 1);
    const int qbase = qidx << 4;
    const int row0 = qbase + rowgrp * 4;

    // M = Wq^T Wk (3x3), w = Wq^T bk, c = bq.bk  (uniform; cheap once)
    float M00=0,M01=0,M02=0,M10=0,M11=0,M12=0,M20=0,M21=0,M22=0;
    float w0=0,w1=0,w2=0,c=0;
#pragma unroll
    for (int d = 0; d < DK; ++d) {
        float q0 = Wq[d*3+0], q1 = Wq[d*3+1], q2 = Wq[d*3+2];
        float k0 = Wk[d*3+0], k1 = Wk[d*3+1], k2 = Wk[d*3+2];
        float bkd = bk[d];
        M00 = fmaf(q0,k0,M00); M01 = fmaf(q0,k1,M01); M02 = fmaf(q0,k2,M02);
        M10 = fmaf(q1,k0,M10); M11 = fmaf(q1,k1,M11); M12 = fmaf(q1,k2,M12);
        M20 = fmaf(q2,k0,M20); M21 = fmaf(q2,k1,M21); M22 = fmaf(q2,k2,M22);
        w0 = fmaf(q0,bkd,w0); w1 = fmaf(q1,bkd,w1); w2 = fmaf(q2,bkd,w2);
        c  = fmaf(bq[d],bkd,c);
    }

    // per-row a = LAM * M^T xq (3), e = LAM * (w.xq + c)
    float a[4][3], e[4];
#pragma unroll
    for (int r = 0; r < 4; ++r) {
        const float* xr = &x[((size_t)b * SS + row0 + r) * 3];
        float x0 = xr[0], x1 = xr[1], x2 = xr[2];
        a[r][0] = LAM * (x0*M00 + x1*M10 + x2*M20);
        a[r][1] = LAM * (x0*M01 + x1*M11 + x2*M21);
        a[r][2] = LAM * (x0*M02 + x1*M12 + x2*M22);
        e[r]    = LAM * (fmaf(x0,w0, fmaf(x1,w1, fmaf(x2,w2, c))));
    }

    float l[4] = {0.f,0.f,0.f,0.f};
    float acc[4][DK] = {};

    const float* KtB = Kt + (size_t)b * 4 * SS;
    const float* VtB = Vt + (size_t)b * DK * SS;

    for (int t = 0; t < SS; t += TK) {
        const bool anyPast = (t <= qbase + 15);   // tile has causal keys -> need V
        __syncthreads();
#pragma unroll
        for (int it = 0; it < 4; ++it) {          // stage K' [4][TK]
            int idx = it * NT + tid;
            int d = idx >> 8, c4 = idx & 255;
            *(float4*)&kls[d][c4 * 4] = *(const float4*)&KtB[(size_t)d * SS + t + c4 * 4];
        }
        if (anyPast) {
#pragma unroll
            for (int it = 0; it < 5; ++it) {      // stage V [5][TK]
                int idx = it * NT + tid;
                int d = idx >> 8, c4 = idx & 255;
                *(float4*)&vls[d][c4 * 4] = *(const float4*)&VtB[(size_t)d * SS + t + c4 * 4];
            }
        }
        __syncthreads();

        if (t + TK <= qbase) {
            // ---- pure past: all keys causal for all our rows ----
#pragma unroll
            for (int j = 0; j < 4; ++j) {
                const int key = j * 256 + sub * 4;
                float kx[4][4], vx[DK][4];
#pragma unroll
                for (int d = 0; d < 4; ++d) *(float4*)kx[d] = *(const float4*)&kls[d][key];
#pragma unroll
                for (int d = 0; d < DK; ++d) *(float4*)vx[d] = *(const float4*)&vls[d][key];
#pragma unroll
                for (int r = 0; r < 4; ++r) {
#pragma unroll
                    for (int kk = 0; kk < 4; ++kk) {
                        float sc = fmaf(a[r][0], kx[0][kk],
                                   fmaf(a[r][1], kx[1][kk],
                                   fmaf(a[r][2], kx[2][kk], e[r] + kx[3][kk])));
                        float p = fast_exp2(sc);
                        l[r] += p;
#pragma unroll
                        for (int d = 0; d < DK; ++d)
                            acc[r][d] = fmaf(p, vx[d][kk], acc[r][d]);
                    }
                }
            }
        } else if (t >= qbase + 16) {
            // ---- pure future: denominator only ----
#pragma unroll
            for (int j = 0; j < 4; ++j) {
                const int key = j * 256 + sub * 4;
                float kx[4][4];
#pragma unroll
                for (int d = 0; d < 4; ++d) *(float4*)kx[d] = *(const float4*)&kls[d][key];
#pragma unroll
                for (int r = 0; r < 4; ++r) {
                    float ps = 0.f;
#pragma unroll
                    for (int kk = 0; kk < 4; ++kk) {
                        float sc = fmaf(a[r][0], kx[0][kk],
                                   fmaf(a[r][1], kx[1][kk],
                                   fmaf(a[r][2], kx[2][kk], e[r] + kx[3][kk])));
                        ps += fast_exp2(sc);
                    }
                    l[r] += ps;
                }
            }
        } else {
            // ---- mixed tile (exactly one per block) ----
#pragma unroll
            for (int j = 0; j < 4; ++j) {
                const int key = j * 256 + sub * 4;
                const int kg = t + key;
                float kx[4][4];
#pragma unroll
                for (int d = 0; d < 4; ++d) *(float4*)kx[d] = *(const float4*)&kls[d][key];

                if (kg + 3 < row0) {
                    float vx[DK][4];
#pragma unroll
                    for (int d = 0; d < DK; ++d) *(float4*)vx[d] = *(const float4*)&vls[d][key];
#pragma unroll
                    for (int r = 0; r < 4; ++r) {
#pragma unroll
                        for (int kk = 0; kk < 4; ++kk) {
                            float sc = fmaf(a[r][0], kx[0][kk],
                                       fmaf(a[r][1], kx[1][kk],
                                       fmaf(a[r][2], kx[2][kk], e[r] + kx[3][kk])));
                            float p = fast_exp2(sc);
                            l[r] += p;
#pragma unroll
                            for (int d = 0; d < DK; ++d)
                                acc[r][d] = fmaf(p, vx[d][kk], acc[r][d]);
                        }
                    }
                } else if (kg > row0 + 3) {
#pragma unroll
                    for (int r = 0; r < 4; ++r) {
                        float ps = 0.f;
#pragma unroll
                        for (int kk = 0; kk < 4; ++kk) {
                            float sc = fmaf(a[r][0], kx[0][kk],
                                       fmaf(a[r][1], kx[1][kk],
                                       fmaf(a[r][2], kx[2][kk], e[r] + kx[3][kk])));
                            ps += fast_exp2(sc);
                        }
                        l[r] += ps;
                    }
                } else {
                    float vx[DK][4];
#pragma unroll
                    for (int d = 0; d < DK; ++d) *(float4*)vx[d] = *(const float4*)&vls[d][key];
#pragma unroll
                    for (int r = 0; r < 4; ++r) {
                        const int row = row0 + r;
#pragma unroll
                        for (int kk = 0; kk < 4; ++kk) {
                            float sc = fmaf(a[r][0], kx[0][kk],
                                       fmaf(a[r][1], kx[1][kk],
                                       fmaf(a[r][2], kx[2][kk], e[r] + kx[3][kk])));
                            float p = fast_exp2(sc);
                            l[r] += p;
                            float pm = (kg + kk <= row) ? p : 0.f;
#pragma unroll
                            for (int d = 0; d < DK; ++d)
                                acc[r][d] = fmaf(pm, vx[d][kk], acc[r][d]);
                        }
                    }
                }
            }
        }
    }

    // epilogue: butterfly-reduce l, acc across the 64 key-split lanes
#pragma unroll
    for (int r = 0; r < 4; ++r) {
        float lr = l[r];
        float a0 = acc[r][0], a1 = acc[r][1], a2 = acc[r][2], a3 = acc[r][3], a4 = acc[r][4];
#pragma unroll
        for (int off = 32; off >= 1; off >>= 1) {
            lr += __shfl_xor(lr, off);
            a0 += __shfl_xor(a0, off);
            a1 += __shfl_xor(a1, off);
            a2 += __shfl_xor(a2, off);
            a3 += __shfl_xor(a3, off);
            a4 += __shfl_xor(a4, off);
        }
        if (sub < DK) {
            float av = sub == 0 ? a0 : sub == 1 ? a1 : sub == 2 ? a2 : sub == 3 ? a3 : a4;
            out[((size_t)b * SS + row0 + r) * DK + sub] = av / lr;
        }
    }
}

extern "C" void kernel_launch(void* const* d_in, const int* in_sizes, int n_in,
                              void* d_out, int out_size, void* d_ws, size_t ws_size,
                              hipStream_t stream) {
    const float* x  = (const float*)d_in[0];
    const float* Wq = (const float*)d_in[1];
    const float* bq = (const float*)d_in[2];
    const float* Wk = (const float*)d_in[3];
    const float* bk = (const float*)d_in[4];
    const float* Wv = (const float*)d_in[5];
    const float* bv = (const float*)d_in[6];
    float* outp = (float*)d_out;

    float* Kt = (float*)d_ws;                       // [B][4][S]  (x0,x1,x2,g)
    float* Vt = Kt + (size_t)BB * 4 * SS;           // [B][5][S]

    proj_kv<<<(BB * SS + NT - 1) / NT, NT, 0, stream>>>(x, Wk, bq, Wv, bv, Kt, Vt);
    attn<<<BB * (SS / 16), NT, 0, stream>>>(x, Wq, bq, Wk, bk, Kt, Vt, outp);
}

// Round 3
// 38.694 us; speedup vs baseline: 1.9537x; 1.5555x over previous
//
#include <hip/hip_runtime.h>
#include <math.h>

#define BB 4
#define SS 4096
#define DK 5
#define TK 1024
#define NT 256
// (1/sqrt(5)) * log2(e) folded into all score terms so p = v_exp_f32(score)
#define LAM (0.44721359549995793f * 1.4426950408889634f)

__device__ __forceinline__ float fast_exp2(float x) {
#if __has_builtin(__builtin_amdgcn_exp2f)
    return __builtin_amdgcn_exp2f(x);
#else
    float r; asm("v_exp_f32 %0, %1" : "=v"(r) : "v"(x)); return r;
#endif
}

// async global->LDS, 16B per lane (dest must be lane-contiguous; ours is)
#define GLOAD16(gp, lp)                                                        \
    __builtin_amdgcn_global_load_lds(                                          \
        (const __attribute__((address_space(1))) unsigned int*)(gp),           \
        (__attribute__((address_space(3))) unsigned int*)(lp), 16, 0, 0)

// ---------------------------------------------------------------------------
// Kernel 1: K' = [x0,x1,x2,g] with g = LAM*(Wk^T bq)·x  (covers the bq-cross
// term; the per-ROW bias terms cancel between numerator and denominator and
// are dropped entirely). V^T = [B][5][S].
// ---------------------------------------------------------------------------
__global__ __launch_bounds__(NT) void proj_kv(
    const float* __restrict__ x,
    const float* __restrict__ Wk, const float* __restrict__ bq,
    const float* __restrict__ Wv, const float* __restrict__ bv,
    float* __restrict__ Kt, float* __restrict__ Vt)
{
    int gid = blockIdx.x * NT + threadIdx.x;
    if (gid >= BB * SS) return;
    int b = gid >> 12;
    int s = gid & (SS - 1);
    float x0 = x[gid * 3 + 0];
    float x1 = x[gid * 3 + 1];
    float x2 = x[gid * 3 + 2];

    float u0 = 0.f, u1 = 0.f, u2 = 0.f;   // u = Wk^T bq
#pragma unroll
    for (int d = 0; d < DK; ++d) {
        float bqd = bq[d];
        u0 = fmaf(Wk[d * 3 + 0], bqd, u0);
        u1 = fmaf(Wk[d * 3 + 1], bqd, u1);
        u2 = fmaf(Wk[d * 3 + 2], bqd, u2);
    }
    float g = LAM * (u0 * x0 + u1 * x1 + u2 * x2);

    float* KtB = Kt + (size_t)b * 4 * SS;
    KtB[0 * SS + s] = x0;
    KtB[1 * SS + s] = x1;
    KtB[2 * SS + s] = x2;
    KtB[3 * SS + s] = g;

#pragma unroll
    for (int d = 0; d < DK; ++d) {
        float vv = fmaf(Wv[d * 3 + 0], x0, fmaf(Wv[d * 3 + 1], x1, fmaf(Wv[d * 3 + 2], x2, bv[d])));
        Vt[((size_t)b * DK + d) * SS + s] = vv;
    }
}

// ---------------------------------------------------------------------------
// Kernel 2: attention. 1024 blocks; each block = low 8-row tile i + mirror
// tile 511-i (constant total work per block). 4 waves: w0,w1 -> low rows,
// w2,w3 -> high rows; each thread 4 rows x 64-lane key split.
// score = a_q · x_k + g_k (pre-scaled), p = exp2(score).
// denominator: all keys; numerator: keys <= row (mask-after-softmax).
// ---------------------------------------------------------------------------
__global__ __launch_bounds__(NT, 4) void attn(
    const float* __restrict__ x,
    const float* __restrict__ Wq, const float* __restrict__ Wk,
    const float* __restrict__ Kt, const float* __restrict__ Vt,
    float* __restrict__ out)
{
    __shared__ float kls[4][TK];
    __shared__ float vls[DK][TK];

    const int tid = threadIdx.x;
    const int sub = tid & 63;
    const int wave = tid >> 6;       // 0..3

    const int b = blockIdx.x >> 8;
    const int i = blockIdx.x & 255;
    const int lowRow  = i * 8;
    const int highRow = (511 - i) * 8;
    // this wave's 4 rows:
    const int row0w = (wave < 2) ? (lowRow + wave * 4) : (highRow + (wave - 2) * 4);
    const int rowMaxBlk = highRow + 7;

    // M = Wq^T Wk (3x3), uniform
    float M00=0,M01=0,M02=0,M10=0,M11=0,M12=0,M20=0,M21=0,M22=0;
#pragma unroll
    for (int d = 0; d < DK; ++d) {
        float q0 = Wq[d*3+0], q1 = Wq[d*3+1], q2 = Wq[d*3+2];
        float k0 = Wk[d*3+0], k1 = Wk[d*3+1], k2 = Wk[d*3+2];
        M00 = fmaf(q0,k0,M00); M01 = fmaf(q0,k1,M01); M02 = fmaf(q0,k2,M02);
        M10 = fmaf(q1,k0,M10); M11 = fmaf(q1,k1,M11); M12 = fmaf(q1,k2,M12);
        M20 = fmaf(q2,k0,M20); M21 = fmaf(q2,k1,M21); M22 = fmaf(q2,k2,M22);
    }

    // per-row a = LAM * (xq^T M)
    float a[4][3];
#pragma unroll
    for (int r = 0; r < 4; ++r) {
        const float* xr = &x[((size_t)b * SS + row0w + r) * 3];
        float x0 = xr[0], x1 = xr[1], x2 = xr[2];
        a[r][0] = LAM * (x0*M00 + x1*M10 + x2*M20);
        a[r][1] = LAM * (x0*M01 + x1*M11 + x2*M21);
        a[r][2] = LAM * (x0*M02 + x1*M12 + x2*M22);
    }

    float l[4] = {0.f,0.f,0.f,0.f};
    float acc[4][DK] = {};

    const float* KtB = Kt + (size_t)b * 4 * SS;
    const float* VtB = Vt + (size_t)b * DK * SS;

    for (int t = 0; t < SS; t += TK) {
        const bool needV = (t <= rowMaxBlk);   // block-uniform
        __syncthreads();                        // previous tile fully consumed
        {
            // stage K' [4][TK]: 4 x (256 lanes x 16B), lane-contiguous
            int d = tid >> 8;                   // always 0 for NT=256; use idx form
#pragma unroll
            for (int it = 0; it < 4; ++it) {
                int idx = it * NT + tid;
                d = idx >> 8;
                int c4 = idx & 255;
                GLOAD16(&KtB[(size_t)d * SS + t + c4 * 4], &kls[d][c4 * 4]);
            }
            if (needV) {
#pragma unroll
                for (int it = 0; it < 5; ++it) {
                    int idx = it * NT + tid;
                    int dd = idx >> 8;
                    int c4 = idx & 255;
                    GLOAD16(&VtB[(size_t)dd * SS + t + c4 * 4], &vls[dd][c4 * 4]);
                }
            }
        }
        __syncthreads();                        // staged (drains vmcnt)

#pragma unroll
        for (int j = 0; j < TK / 256; ++j) {
            const int key = j * 256 + sub * 4;
            const int cstart = t + j * 256;     // wave-uniform chunk bounds
            const int cend   = cstart + 255;

            float kx[4][4];
#pragma unroll
            for (int d = 0; d < 4; ++d)
                *(float4*)kx[d] = *(const float4*)&kls[d][key];

            if (cend <= row0w) {
                // ---- all-past for this wave ----
                float vx[DK][4];
#pragma unroll
                for (int d = 0; d < DK; ++d)
                    *(float4*)vx[d] = *(const float4*)&vls[d][key];
#pragma unroll
                for (int r = 0; r < 4; ++r) {
                    float ps = 0.f;
#pragma unroll
                    for (int kk = 0; kk < 4; ++kk) {
                        float sc = fmaf(a[r][0], kx[0][kk],
                                   fmaf(a[r][1], kx[1][kk],
                                   fmaf(a[r][2], kx[2][kk], kx[3][kk])));
                        float p = fast_exp2(sc);
                        ps += p;
#pragma unroll
                        for (int d = 0; d < DK; ++d)
                            acc[r][d] = fmaf(p, vx[d][kk], acc[r][d]);
                    }
                    l[r] += ps;
                }
            } else if (cstart > row0w + 3) {
                // ---- all-future: denominator only ----
#pragma unroll
                for (int r = 0; r < 4; ++r) {
                    float ps = 0.f;
#pragma unroll
                    for (int kk = 0; kk < 4; ++kk) {
                        float sc = fmaf(a[r][0], kx[0][kk],
                                   fmaf(a[r][1], kx[1][kk],
                                   fmaf(a[r][2], kx[2][kk], kx[3][kk])));
                        ps += fast_exp2(sc);
                    }
                    l[r] += ps;
                }
            } else {
                // ---- boundary chunk (exactly one per wave) ----
                const int kg = t + key;
                float vx[DK][4];
#pragma unroll
                for (int d = 0; d < DK; ++d)
                    *(float4*)vx[d] = *(const float4*)&vls[d][key];
#pragma unroll
                for (int r = 0; r < 4; ++r) {
                    const int row = row0w + r;
                    float ps = 0.f;
#pragma unroll
                    for (int kk = 0; kk < 4; ++kk) {
                        float sc = fmaf(a[r][0], kx[0][kk],
                                   fmaf(a[r][1], kx[1][kk],
                                   fmaf(a[r][2], kx[2][kk], kx[3][kk])));
                        float p = fast_exp2(sc);
                        ps += p;
                        float pm = (kg + kk <= row) ? p : 0.f;
#pragma unroll
                        for (int d = 0; d < DK; ++d)
                            acc[r][d] = fmaf(pm, vx[d][kk], acc[r][d]);
                    }
                    l[r] += ps;
                }
            }
        }
    }

    // butterfly-reduce l, acc across the 64 key-split lanes
#pragma unroll
    for (int r = 0; r < 4; ++r) {
        float lr = l[r];
        float a0 = acc[r][0], a1 = acc[r][1], a2 = acc[r][2], a3 = acc[r][3], a4 = acc[r][4];
#pragma unroll
        for (int off = 32; off >= 1; off >>= 1) {
            lr += __shfl_xor(lr, off);
            a0 += __shfl_xor(a0, off);
            a1 += __shfl_xor(a1, off);
            a2 += __shfl_xor(a2, off);
            a3 += __shfl_xor(a3, off);
            a4 += __shfl_xor(a4, off);
        }
        if (sub < DK) {
            float av = sub == 0 ? a0 : sub == 1 ? a1 : sub == 2 ? a2 : sub == 3 ? a3 : a4;
            out[((size_t)b * SS + row0w + r) * DK + sub] = av / lr;
        }
    }
}

extern "C" void kernel_launch(void* const* d_in, const int* in_sizes, int n_in,
                              void* d_out, int out_size, void* d_ws, size_t ws_size,
                              hipStream_t stream) {
    const float* x  = (const float*)d_in[0];
    const float* Wq = (const float*)d_in[1];
    const float* bq = (const float*)d_in[2];
    const float* Wk = (const float*)d_in[3];
    const float* Wv = (const float*)d_in[5];
    const float* bv = (const float*)d_in[6];
    float* outp = (float*)d_out;

    float* Kt = (float*)d_ws;                       // [B][4][S]  (x0,x1,x2,g)
    float* Vt = Kt + (size_t)BB * 4 * SS;           // [B][5][S]

    proj_kv<<<(BB * SS + NT - 1) / NT, NT, 0, stream>>>(x, Wk, bq, Wv, bv, Kt, Vt);
    attn<<<BB * (SS / 16), NT, 0, stream>>>(x, Wq, Wk, Kt, Vt, outp);
}

// Round 5
// 35.367 us; speedup vs baseline: 2.1375x; 1.0941x over previous
//
#include <hip/hip_runtime.h>
#include <math.h>

#define BB 4
#define SS 4096
#define DK 5
#define TK 1024
#define NT 256
// (1/sqrt(5)) * log2(e) folded into all score terms so p = v_exp_f32(score)
#define LAM (0.44721359549995793f * 1.4426950408889634f)

typedef float v2f __attribute__((ext_vector_type(2)));

__device__ __forceinline__ float fast_exp2(float x) {
#if __has_builtin(__builtin_amdgcn_exp2f)
    return __builtin_amdgcn_exp2f(x);
#else
    float r; asm("v_exp_f32 %0, %1" : "=v"(r) : "v"(x)); return r;
#endif
}

// Packed fp32: compiler selects v_pk_fma_f32 on gfx90a+ for <2 x float> fma
// (correct hazards/alignment guaranteed; falls back to 2x v_fma_f32 if not).
__device__ __forceinline__ v2f pk_fma(v2f a, v2f b, v2f c) {
    return __builtin_elementwise_fma(a, b, c);
}

// async global->LDS, 16B per lane (dest lane-contiguous)
#define GLOAD16(gp, lp)                                                        \
    __builtin_amdgcn_global_load_lds(                                          \
        (const __attribute__((address_space(1))) unsigned int*)(gp),           \
        (__attribute__((address_space(3))) unsigned int*)(lp), 16, 0, 0)

// ---------------------------------------------------------------------------
// Kernel 1: K' = [x0,x1,x2,g], g = LAM*(Wk^T bq)·x  (bq cross-term; per-row
// bias terms cancel in numerator/denominator). V^T = [B][5][S].
// ---------------------------------------------------------------------------
__global__ __launch_bounds__(NT) void proj_kv(
    const float* __restrict__ x,
    const float* __restrict__ Wk, const float* __restrict__ bq,
    const float* __restrict__ Wv, const float* __restrict__ bv,
    float* __restrict__ Kt, float* __restrict__ Vt)
{
    int gid = blockIdx.x * NT + threadIdx.x;
    if (gid >= BB * SS) return;
    int b = gid >> 12;
    int s = gid & (SS - 1);
    float x0 = x[gid * 3 + 0];
    float x1 = x[gid * 3 + 1];
    float x2 = x[gid * 3 + 2];

    float u0 = 0.f, u1 = 0.f, u2 = 0.f;   // u = Wk^T bq
#pragma unroll
    for (int d = 0; d < DK; ++d) {
        float bqd = bq[d];
        u0 = fmaf(Wk[d * 3 + 0], bqd, u0);
        u1 = fmaf(Wk[d * 3 + 1], bqd, u1);
        u2 = fmaf(Wk[d * 3 + 2], bqd, u2);
    }
    float g = LAM * (u0 * x0 + u1 * x1 + u2 * x2);

    float* KtB = Kt + (size_t)b * 4 * SS;
    KtB[0 * SS + s] = x0;
    KtB[1 * SS + s] = x1;
    KtB[2 * SS + s] = x2;
    KtB[3 * SS + s] = g;

#pragma unroll
    for (int d = 0; d < DK; ++d) {
        float vv = fmaf(Wv[d * 3 + 0], x0, fmaf(Wv[d * 3 + 1], x1, fmaf(Wv[d * 3 + 2], x2, bv[d])));
        Vt[((size_t)b * DK + d) * SS + s] = vv;
    }
}

// ---------------------------------------------------------------------------
// Kernel 2: attention, packed-fp32 inner loop (compiler-formed VOP3P).
// Block = low 8-row tile i + mirror tile 511-i (constant work/block).
// 4 waves x 4 rows/thread x 64-lane key split.
// score = a_q·x_k + g_k (pre-scaled), p = exp2(score).
// Denominator: all keys; numerator: keys <= row (mask-after-softmax).
// ---------------------------------------------------------------------------
__global__ __launch_bounds__(NT, 4) void attn(
    const float* __restrict__ x,
    const float* __restrict__ Wq, const float* __restrict__ Wk,
    const float* __restrict__ Kt, const float* __restrict__ Vt,
    float* __restrict__ out)
{
    __shared__ float kls[4][TK];
    __shared__ float vls[DK][TK];

    const int tid = threadIdx.x;
    const int sub = tid & 63;
    const int wave = tid >> 6;

    const int b = blockIdx.x >> 8;
    const int i = blockIdx.x & 255;
    const int lowRow  = i * 8;
    const int highRow = (511 - i) * 8;
    const int row0w = (wave < 2) ? (lowRow + wave * 4) : (highRow + (wave - 2) * 4);
    const int rowMaxBlk = highRow + 7;

    // M = Wq^T Wk (3x3), uniform
    float M00=0,M01=0,M02=0,M10=0,M11=0,M12=0,M20=0,M21=0,M22=0;
#pragma unroll
    for (int d = 0; d < DK; ++d) {
        float q0 = Wq[d*3+0], q1 = Wq[d*3+1], q2 = Wq[d*3+2];
        float k0 = Wk[d*3+0], k1 = Wk[d*3+1], k2 = Wk[d*3+2];
        M00 = fmaf(q0,k0,M00); M01 = fmaf(q0,k1,M01); M02 = fmaf(q0,k2,M02);
        M10 = fmaf(q1,k0,M10); M11 = fmaf(q1,k1,M11); M12 = fmaf(q1,k2,M12);
        M20 = fmaf(q2,k0,M20); M21 = fmaf(q2,k1,M21); M22 = fmaf(q2,k2,M22);
    }

    // per-row a (broadcast into both packed halves)
    v2f a2[4][3];
#pragma unroll
    for (int r = 0; r < 4; ++r) {
        const float* xr = &x[((size_t)b * SS + row0w + r) * 3];
        float x0 = xr[0], x1 = xr[1], x2 = xr[2];
        float av0 = LAM * (x0*M00 + x1*M10 + x2*M20);
        float av1 = LAM * (x0*M01 + x1*M11 + x2*M21);
        float av2 = LAM * (x0*M02 + x1*M12 + x2*M22);
        a2[r][0] = (v2f){av0, av0};
        a2[r][1] = (v2f){av1, av1};
        a2[r][2] = (v2f){av2, av2};
    }

    float l[4] = {0.f,0.f,0.f,0.f};
    v2f acc2[4][DK];
#pragma unroll
    for (int r = 0; r < 4; ++r)
#pragma unroll
        for (int d = 0; d < DK; ++d) acc2[r][d] = (v2f){0.f, 0.f};

    const float* KtB = Kt + (size_t)b * 4 * SS;
    const float* VtB = Vt + (size_t)b * DK * SS;

    for (int t = 0; t < SS; t += TK) {
        const bool needV = (t <= rowMaxBlk);   // block-uniform
        __syncthreads();
#pragma unroll
        for (int it = 0; it < 4; ++it) {
            int idx = it * NT + tid;
            int d = idx >> 8, c4 = idx & 255;
            GLOAD16(&KtB[(size_t)d * SS + t + c4 * 4], &kls[d][c4 * 4]);
        }
        if (needV) {
#pragma unroll
            for (int it = 0; it < 5; ++it) {
                int idx = it * NT + tid;
                int dd = idx >> 8, c4 = idx & 255;
                GLOAD16(&VtB[(size_t)dd * SS + t + c4 * 4], &vls[dd][c4 * 4]);
            }
        }
        __syncthreads();

#pragma unroll
        for (int j = 0; j < TK / 256; ++j) {
            const int key = j * 256 + sub * 4;
            const int cstart = t + j * 256;
            const int cend   = cstart + 255;

            float4 kt0 = *(const float4*)&kls[0][key];
            float4 kt1 = *(const float4*)&kls[1][key];
            float4 kt2 = *(const float4*)&kls[2][key];
            float4 kt3 = *(const float4*)&kls[3][key];
            v2f kA0 = ((v2f*)&kt0)[0], kB0 = ((v2f*)&kt0)[1];
            v2f kA1 = ((v2f*)&kt1)[0], kB1 = ((v2f*)&kt1)[1];
            v2f kA2 = ((v2f*)&kt2)[0], kB2 = ((v2f*)&kt2)[1];
            v2f gA  = ((v2f*)&kt3)[0], gB  = ((v2f*)&kt3)[1];

            if (cend <= row0w) {
                // ---- all-past ----
                v2f vA[DK], vB[DK];
#pragma unroll
                for (int d = 0; d < DK; ++d) {
                    float4 vt = *(const float4*)&vls[d][key];
                    vA[d] = ((v2f*)&vt)[0]; vB[d] = ((v2f*)&vt)[1];
                }
#pragma unroll
                for (int r = 0; r < 4; ++r) {
                    v2f scA = pk_fma(a2[r][0], kA0, pk_fma(a2[r][1], kA1, pk_fma(a2[r][2], kA2, gA)));
                    v2f scB = pk_fma(a2[r][0], kB0, pk_fma(a2[r][1], kB1, pk_fma(a2[r][2], kB2, gB)));
                    v2f pA, pB;
                    pA.x = fast_exp2(scA.x); pA.y = fast_exp2(scA.y);
                    pB.x = fast_exp2(scB.x); pB.y = fast_exp2(scB.y);
                    v2f ps = pA + pB;
                    l[r] += ps.x + ps.y;
#pragma unroll
                    for (int d = 0; d < DK; ++d) {
                        acc2[r][d] = pk_fma(pA, vA[d], acc2[r][d]);
                        acc2[r][d] = pk_fma(pB, vB[d], acc2[r][d]);
                    }
                }
            } else if (cstart > row0w + 3) {
                // ---- all-future: denominator only ----
#pragma unroll
                for (int r = 0; r < 4; ++r) {
                    v2f scA = pk_fma(a2[r][0], kA0, pk_fma(a2[r][1], kA1, pk_fma(a2[r][2], kA2, gA)));
                    v2f scB = pk_fma(a2[r][0], kB0, pk_fma(a2[r][1], kB1, pk_fma(a2[r][2], kB2, gB)));
                    v2f pA, pB;
                    pA.x = fast_exp2(scA.x); pA.y = fast_exp2(scA.y);
                    pB.x = fast_exp2(scB.x); pB.y = fast_exp2(scB.y);
                    v2f ps = pA + pB;
                    l[r] += ps.x + ps.y;
                }
            } else {
                // ---- boundary chunk (one per wave) ----
                const int kg = t + key;
                v2f vA[DK], vB[DK];
#pragma unroll
                for (int d = 0; d < DK; ++d) {
                    float4 vt = *(const float4*)&vls[d][key];
                    vA[d] = ((v2f*)&vt)[0]; vB[d] = ((v2f*)&vt)[1];
                }
#pragma unroll
                for (int r = 0; r < 4; ++r) {
                    const int row = row0w + r;
                    v2f scA = pk_fma(a2[r][0], kA0, pk_fma(a2[r][1], kA1, pk_fma(a2[r][2], kA2, gA)));
                    v2f scB = pk_fma(a2[r][0], kB0, pk_fma(a2[r][1], kB1, pk_fma(a2[r][2], kB2, gB)));
                    v2f pA, pB;
                    pA.x = fast_exp2(scA.x); pA.y = fast_exp2(scA.y);
                    pB.x = fast_exp2(scB.x); pB.y = fast_exp2(scB.y);
                    v2f ps = pA + pB;
                    l[r] += ps.x + ps.y;
                    v2f pmA, pmB;
                    pmA.x = (kg + 0 <= row) ? pA.x : 0.f;
                    pmA.y = (kg + 1 <= row) ? pA.y : 0.f;
                    pmB.x = (kg + 2 <= row) ? pB.x : 0.f;
                    pmB.y = (kg + 3 <= row) ? pB.y : 0.f;
#pragma unroll
                    for (int d = 0; d < DK; ++d) {
                        acc2[r][d] = pk_fma(pmA, vA[d], acc2[r][d]);
                        acc2[r][d] = pk_fma(pmB, vB[d], acc2[r][d]);
                    }
                }
            }
        }
    }

    // fold packed halves, then butterfly-reduce across the 64 key-split lanes
#pragma unroll
    for (int r = 0; r < 4; ++r) {
        float lr = l[r];
        float a0 = acc2[r][0].x + acc2[r][0].y;
        float a1 = acc2[r][1].x + acc2[r][1].y;
        float a2_ = acc2[r][2].x + acc2[r][2].y;
        float a3 = acc2[r][3].x + acc2[r][3].y;
        float a4 = acc2[r][4].x + acc2[r][4].y;
#pragma unroll
        for (int off = 32; off >= 1; off >>= 1) {
            lr  += __shfl_xor(lr, off);
            a0  += __shfl_xor(a0, off);
            a1  += __shfl_xor(a1, off);
            a2_ += __shfl_xor(a2_, off);
            a3  += __shfl_xor(a3, off);
            a4  += __shfl_xor(a4, off);
        }
        if (sub < DK) {
            float av = sub == 0 ? a0 : sub == 1 ? a1 : sub == 2 ? a2_ : sub == 3 ? a3 : a4;
            out[((size_t)b * SS + row0w + r) * DK + sub] = av / lr;
        }
    }
}

extern "C" void kernel_launch(void* const* d_in, const int* in_sizes, int n_in,
                              void* d_out, int out_size, void* d_ws, size_t ws_size,
                              hipStream_t stream) {
    const float* x  = (const float*)d_in[0];
    const float* Wq = (const float*)d_in[1];
    const float* bq = (const float*)d_in[2];
    const float* Wk = (const float*)d_in[3];
    const float* Wv = (const float*)d_in[5];
    const float* bv = (const float*)d_in[6];
    float* outp = (float*)d_out;

    float* Kt = (float*)d_ws;                       // [B][4][S]  (x0,x1,x2,g)
    float* Vt = Kt + (size_t)BB * 4 * SS;           // [B][5][S]

    proj_kv<<<(BB * SS + NT - 1) / NT, NT, 0, stream>>>(x, Wk, bq, Wv, bv, Kt, Vt);
    attn<<<BB * (SS / 16), NT, 0, stream>>>(x, Wq, Wk, Kt, Vt, outp);
}